// Round 12
// baseline (226.030 us; speedup 1.0000x reference)
//
#include <hip/hip_runtime.h>
#include <hip/hip_bf16.h>

#define B 128
#define N 1024
#define L 512
#define D 64

typedef float f32x4 __attribute__((ext_vector_type(4)));
typedef short bf16x8 __attribute__((ext_vector_type(8)));

// 8 fp32 -> 8 bf16 (RNE) via packed HW cvt
__device__ inline bf16x8 cvt8(float4 f0, float4 f1) {
    union { __hip_bfloat162 h2[4]; bf16x8 v; } u;
    u.h2[0] = __float22bfloat162_rn(make_float2(f0.x, f0.y));
    u.h2[1] = __float22bfloat162_rn(make_float2(f0.z, f0.w));
    u.h2[2] = __float22bfloat162_rn(make_float2(f1.x, f1.y));
    u.h2[3] = __float22bfloat162_rn(make_float2(f1.z, f1.w));
    return u.v;
}

// async global->LDS DMA, 16B per lane; LDS dest = wave-uniform base + lane*16
__device__ __forceinline__ void gload16(const void* g, void* l) {
    __builtin_amdgcn_global_load_lds(
        (const __attribute__((address_space(1))) void*)g,
        (__attribute__((address_space(3))) void*)l, 16, 0, 0);
}

// ============================ bf16-workspace path ============================
// Fused pre-pass: blocks [0,B): mask counts; blocks [B,B+512): I fp32->bf16.
__global__ __launch_bounds__(256) void prep_kernel(
        const float* __restrict__ tmask, const float* __restrict__ imask,
        const float* __restrict__ I,
        int* __restrict__ counts, unsigned short* __restrict__ Ibf) {
    int blk = blockIdx.x, tid = threadIdx.x;
    if (blk < B) {
        int b = blk;
        int w = tid >> 6, lane = tid & 63;
        float ts = 0.f, is = 0.f;
        const float* tm = tmask + (size_t)b * N;
#pragma unroll
        for (int i = 0; i < N / 256; ++i) ts += tm[tid + i * 256];
        const float* im = imask + (size_t)b * L;
#pragma unroll
        for (int i = 0; i < L / 256; ++i) is += im[tid + i * 256];
        for (int off = 32; off; off >>= 1) {
            ts += __shfl_down(ts, off);
            is += __shfl_down(is, off);
        }
        __shared__ float red[8];
        if (lane == 0) { red[w] = ts; red[4 + w] = is; }
        __syncthreads();
        if (tid == 0) counts[b]     = (int)(red[0] + red[1] + red[2] + red[3] + 0.5f);
        if (tid == 1) counts[B + b] = (int)(red[4] + red[5] + red[6] + red[7] + 0.5f);
    } else {
        int t = (blk - B) * 256 + tid;                 // 0..131071
#pragma unroll
        for (int j = 0; j < 4; ++j) {
            size_t ci = (size_t)t + (size_t)j * 131072;
            const float4* p = (const float4*)(I + ci * 8);
            *(bf16x8*)(Ibf + ci * 8) = cvt8(p[0], p[1]);
        }
    }
}

// grid = 1536 blocks (s,b,token-chunk) x 256 thr.
// MAX-TLP variant of the r5-proven pipeline: chunk shrunk 64->32 regions
// (4KB), LDS = 3 x 4KB + red = 12.4KB, __launch_bounds__(256,8) -> 8
// blocks/CU x 4 waves = 32 waves/CU (hardware max; 4x r8/r9, 2x r5). The
// whole grid is resident with slack. Rationale: every structure so far is
// latency-bound on the per-wave dependent chain (ds_read->MFMA->fmax);
// the one knob not yet maxed is TLP.
// Block-cooperative staging (4 waves share each staged chunk — r11's
// per-wave redundancy removed). stage(k) = exactly 1 gload16 per thread
// (1 VMEM instr per wave), so the r5 counted-vmcnt ledger rescales to:
// prologue stage(0,1) [2/wave]; iter k: stage(k+2) [3 out]; end-of-iter
// wait vmcnt(1) => chunk k+1 landed (k+2 still flying), lgkmcnt(0) +
// barrier protects the mod-3 buffer rotation (identical hazard proof).
// Chunk layout (4KB = 32 regions x 64 elems bf16), 16B chunk ci = tid:
//   g=ci>>6 (=rt*2+h, rt in {0,1}), ln=ci&63: region (g>>1)*16+(ln&15),
//   elems (g&1)*32+(ln>>4)*8 .. +8. Conflict-free ds_read_b128 at
//   base+lane*16 + (rt*2+h)*1024.
__global__ __launch_bounds__(256, 8) void sim_kernel_bf16(
        const float* __restrict__ T, const unsigned short* __restrict__ Ibf,
        const int* __restrict__ counts,
        const int* __restrict__ Iimp, const int* __restrict__ Simp,
        float* __restrict__ partials) {
    int blk = blockIdx.x;          // 0..1535
    int chunk = blk & 3;
    int bs = blk >> 2;
    int b = bs & (B - 1);
    int s = bs >> 7;
    int Tb = b, Ib = b;
    if (s == 1) Tb = Simp[b];
    else if (s == 2) Ib = Iimp[b];

    int tid = threadIdx.x;
    int w = tid >> 6;
    int lane = tid & 63;
    int q = lane >> 4;
    int c = lane & 15;

    int ntok = counts[Tb];         // block-uniform
    int nreg = counts[B + Ib];

    int tok0 = chunk << 8;
    if (chunk != 0 && tok0 >= ntok) {      // ntok >= 256: chunk 0 never exits
        if (tid == 0) partials[blk] = 0.f;
        return;
    }

    __shared__ unsigned short ldsI[3][2048];     // 3 x 4KB bf16 chunk buffers
    __shared__ float red[4];

    // ---- A fragments: 4 token tiles x 2 K-halves (rows >= ntok masked at sum)
    int wt0 = tok0 + w * 64;
    bf16x8 afrag[4][2];
#pragma unroll
    for (int tt = 0; tt < 4; ++tt) {
        const float* trow = T + ((size_t)Tb * N + wt0 + tt * 16 + c) * D;
#pragma unroll
        for (int h = 0; h < 2; ++h) {
            const float4* p = (const float4*)(trow + h * 32 + q * 8);
            afrag[tt][h] = cvt8(p[0], p[1]);
        }
    }

    float mx[4][4];
#pragma unroll
    for (int tt = 0; tt < 4; ++tt)
#pragma unroll
        for (int i = 0; i < 4; ++i) mx[tt][i] = -3.0e38f;

    // ---- staging decode: 1 x 16B DMA per thread per 32-region chunk ----
    int g = tid >> 6, ln = tid & 63;
    int rloc = (g >> 1) * 16 + (ln & 15);
    int eoff = (g & 1) * 32 + (ln >> 4) * 8;
    const unsigned short* Ibase = Ibf + (size_t)Ib * L * D;
    int nch = (nreg + 31) >> 5;                  // 4..16 (nreg >= 128)
    int nregm1 = nreg - 1;

    auto stage = [&](int k) {
        int r = (k << 5) + rloc;
        if (r > nregm1) r = nregm1;              // duplicate valid row: max-neutral
        gload16(Ibase + (size_t)r * D + eoff,
                &ldsI[k % 3][0] + (size_t)tid * 8);
    };

    // isolate stage ops in the vmcnt counter (afrag/counts loads all consumed)
    asm volatile("s_waitcnt vmcnt(0)" ::: "memory");
    stage(0);
    stage(1);
    asm volatile("s_waitcnt vmcnt(1)" ::: "memory");   // chunk 0 landed
    __builtin_amdgcn_s_barrier();

    for (int k = 0; k < nch; ++k) {
        if (k + 2 < nch) stage(k + 2);           // depth-2: issue over compute

        // 32-region chunk: 4 ds_read_b128 (conflict-free) + 16 MFMA
        const char* base = (const char*)&ldsI[k % 3][0] + (size_t)lane * 16;
#pragma unroll
        for (int rt = 0; rt < 2; ++rt) {
            bf16x8 b0 = *(const bf16x8*)(base + (rt * 2 + 0) * 1024);
            bf16x8 b1 = *(const bf16x8*)(base + (rt * 2 + 1) * 1024);
#pragma unroll
            for (int tt = 0; tt < 4; ++tt) {
                f32x4 acc = {0.f, 0.f, 0.f, 0.f};
                acc = __builtin_amdgcn_mfma_f32_16x16x32_bf16(afrag[tt][0], b0, acc, 0, 0, 0);
                acc = __builtin_amdgcn_mfma_f32_16x16x32_bf16(afrag[tt][1], b1, acc, 0, 0, 0);
#pragma unroll
                for (int i = 0; i < 4; ++i) mx[tt][i] = fmaxf(mx[tt][i], acc[i]);
            }
        }

        if (k + 1 < nch) {
            // need stage(k+1) landed; stage(k+2) (1 instr/wave) may fly on.
            // lgkmcnt(0): all waves' ds_reads done before barrier -> mod-3 safe
            if (k + 2 < nch)
                asm volatile("s_waitcnt vmcnt(1) lgkmcnt(0)" ::: "memory");
            else
                asm volatile("s_waitcnt vmcnt(0) lgkmcnt(0)" ::: "memory");
            __builtin_amdgcn_s_barrier();
        }
    }

    // ---- cross-lane max over 16 region-cols ----
#pragma unroll
    for (int m = 1; m < 16; m <<= 1) {
#pragma unroll
        for (int tt = 0; tt < 4; ++tt)
#pragma unroll
            for (int i = 0; i < 4; ++i)
                mx[tt][i] = fmaxf(mx[tt][i], __shfl_xor(mx[tt][i], m));
    }

    // ---- masked token sum (C layout: row = q*4 + i) ----
    float bsum = 0.f;
    if (c == 0) {
#pragma unroll
        for (int tt = 0; tt < 4; ++tt)
#pragma unroll
            for (int i = 0; i < 4; ++i) {
                int row = wt0 + tt * 16 + q * 4 + i;
                if (row < ntok) bsum += mx[tt][i];
            }
    }
    for (int off = 32; off; off >>= 1) bsum += __shfl_down(bsum, off);
    if (lane == 0) red[w] = bsum;
    __syncthreads();
    if (tid == 0)
        partials[blk] = (red[0] + red[1] + red[2] + red[3]) / (float)ntok;
}

// ===================== fallback path (tiny workspace, r3) =====================
__global__ __launch_bounds__(256) void count_kernel(
        const float* __restrict__ tmask, const float* __restrict__ imask,
        int* __restrict__ counts) {
    int b = blockIdx.x, tid = threadIdx.x;
    int w = tid >> 6, lane = tid & 63;
    float ts = 0.f, is = 0.f;
    const float* tm = tmask + (size_t)b * N;
#pragma unroll
    for (int i = 0; i < N / 256; ++i) ts += tm[tid + i * 256];
    const float* im = imask + (size_t)b * L;
#pragma unroll
    for (int i = 0; i < L / 256; ++i) is += im[tid + i * 256];
    for (int off = 32; off; off >>= 1) {
        ts += __shfl_down(ts, off);
        is += __shfl_down(is, off);
    }
    __shared__ float red[8];
    if (lane == 0) { red[w] = ts; red[4 + w] = is; }
    __syncthreads();
    if (tid == 0) counts[b]     = (int)(red[0] + red[1] + red[2] + red[3] + 0.5f);
    if (tid == 1) counts[B + b] = (int)(red[4] + red[5] + red[6] + red[7] + 0.5f);
}

// verbatim round-3 sim kernel (passed): fp32 DMA staging, 3x16KB LDS
__global__ __launch_bounds__(256, 3) void sim_kernel_f32(
        const float* __restrict__ T, const float* __restrict__ I,
        const int* __restrict__ counts,
        const int* __restrict__ Iimp, const int* __restrict__ Simp,
        float* __restrict__ partials) {
    int blk = blockIdx.x;
    int chunk = blk & 3;
    int bs = blk >> 2;
    int b = bs & (B - 1);
    int s = bs >> 7;
    int Tb = b, Ib = b;
    if (s == 1) Tb = Simp[b];
    else if (s == 2) Ib = Iimp[b];

    int tid = threadIdx.x;
    int w = tid >> 6;
    int lane = tid & 63;
    int q = lane >> 4;
    int c = lane & 15;

    int ntok = counts[Tb];
    int nreg = counts[B + Ib];

    int tok0 = chunk << 8;
    if (chunk != 0 && tok0 >= ntok) {
        if (tid == 0) partials[blk] = 0.f;
        return;
    }

    __shared__ float ldsI[3][4096];
    __shared__ float red[4];

    int wt0 = tok0 + w * 64;
    bf16x8 afrag[4][2];
#pragma unroll
    for (int tt = 0; tt < 4; ++tt) {
        const float* trow = T + ((size_t)Tb * N + wt0 + tt * 16 + c) * D;
#pragma unroll
        for (int h = 0; h < 2; ++h) {
            const float4* p = (const float4*)(trow + h * 32 + q * 8);
            afrag[tt][h] = cvt8(p[0], p[1]);
        }
    }

    float mx[4][4];
#pragma unroll
    for (int tt = 0; tt < 4; ++tt)
#pragma unroll
        for (int i = 0; i < 4; ++i) mx[tt][i] = -3.0e38f;

    int rloc[4], foff[4];
#pragma unroll
    for (int j = 0; j < 4; ++j) {
        int ci = tid + j * 256;
        int fh = ci >> 7, idx = ci & 127, half = idx >> 6, ln2 = idx & 63;
        rloc[j] = (fh >> 1) * 16 + (ln2 & 15);
        foff[j] = (fh & 1) * 32 + (ln2 >> 4) * 8 + half * 4;
    }
    const float* Ibase = I + (size_t)Ib * L * D;
    int nchunks = (nreg + 63) >> 6;
    int nregm1 = nreg - 1;

    auto stage = [&](int k) {
        float* buf = &ldsI[k % 3][0];
        int rbase = k << 6;
#pragma unroll
        for (int j = 0; j < 4; ++j) {
            int r = rbase + rloc[j];
            if (r > nregm1) r = nregm1;
            gload16(Ibase + (size_t)r * D + foff[j], buf + (tid + j * 256) * 4);
        }
    };

    asm volatile("s_waitcnt vmcnt(0)" ::: "memory");
    stage(0);
    stage(1);
    asm volatile("s_waitcnt vmcnt(4)" ::: "memory");
    __builtin_amdgcn_s_barrier();

    for (int k = 0; k < nchunks; ++k) {
        if (k + 2 < nchunks) stage(k + 2);

        const char* base = (const char*)&ldsI[k % 3][0] + (size_t)lane * 16;
#pragma unroll
        for (int rt = 0; rt < 4; ++rt) {
            float4 e0 = *(const float4*)(base + (rt * 2 + 0) * 2048);
            float4 e1 = *(const float4*)(base + (rt * 2 + 0) * 2048 + 1024);
            float4 e2 = *(const float4*)(base + (rt * 2 + 1) * 2048);
            float4 e3 = *(const float4*)(base + (rt * 2 + 1) * 2048 + 1024);
            bf16x8 b0 = cvt8(e0, e1);
            bf16x8 b1 = cvt8(e2, e3);
#pragma unroll
            for (int tt = 0; tt < 4; ++tt) {
                f32x4 acc = {0.f, 0.f, 0.f, 0.f};
                acc = __builtin_amdgcn_mfma_f32_16x16x32_bf16(afrag[tt][0], b0, acc, 0, 0, 0);
                acc = __builtin_amdgcn_mfma_f32_16x16x32_bf16(afrag[tt][1], b1, acc, 0, 0, 0);
#pragma unroll
                for (int i = 0; i < 4; ++i) mx[tt][i] = fmaxf(mx[tt][i], acc[i]);
            }
        }

        if (k + 1 < nchunks) {
            if (k + 2 < nchunks)
                asm volatile("s_waitcnt vmcnt(4) lgkmcnt(0)" ::: "memory");
            else
                asm volatile("s_waitcnt vmcnt(0) lgkmcnt(0)" ::: "memory");
            __builtin_amdgcn_s_barrier();
        }
    }

#pragma unroll
    for (int m = 1; m < 16; m <<= 1) {
#pragma unroll
        for (int tt = 0; tt < 4; ++tt)
#pragma unroll
            for (int i = 0; i < 4; ++i)
                mx[tt][i] = fmaxf(mx[tt][i], __shfl_xor(mx[tt][i], m));
    }

    float bsum = 0.f;
    if (c == 0) {
#pragma unroll
        for (int tt = 0; tt < 4; ++tt)
#pragma unroll
            for (int i = 0; i < 4; ++i) {
                int row = wt0 + tt * 16 + q * 4 + i;
                if (row < ntok) bsum += mx[tt][i];
            }
    }
    for (int off = 32; off; off >>= 1) bsum += __shfl_down(bsum, off);
    if (lane == 0) red[w] = bsum;
    __syncthreads();
    if (tid == 0)
        partials[blk] = (red[0] + red[1] + red[2] + red[3]) / (float)ntok;
}

// 1 block x 384 threads: fold 1536 partials -> 384 sims -> hinge -> loss
__global__ void loss_kernel(const float* __restrict__ partials,
                            float* __restrict__ out) {
    int tid = threadIdx.x;  // 0..383
    __shared__ float simsL[384];
    __shared__ float w6[6];
    const float4* p4 = (const float4*)partials;
    float4 v = p4[tid];
    simsL[tid] = v.x + v.y + v.z + v.w;
    __syncthreads();
    float per = 0.f;
    if (tid < B) {
        float anc  = simsL[tid];
        float simp = simsL[B + tid];
        float iimp = simsL[2 * B + tid];
        per = fmaxf(1.f + iimp - anc, 0.f) + fmaxf(1.f + simp - anc, 0.f);
    }
    for (int off = 32; off; off >>= 1) per += __shfl_down(per, off);
    if ((tid & 63) == 0) w6[tid >> 6] = per;
    __syncthreads();
    if (tid == 0)
        out[0] = (w6[0] + w6[1] + w6[2] + w6[3] + w6[4] + w6[5]) / (float)B;
}

extern "C" void kernel_launch(void* const* d_in, const int* in_sizes, int n_in,
                              void* d_out, int out_size, void* d_ws, size_t ws_size,
                              hipStream_t stream) {
    const float* T     = (const float*)d_in[0];
    const float* I     = (const float*)d_in[1];
    const float* tmask = (const float*)d_in[2];
    const float* imask = (const float*)d_in[3];
    const int*   Iimp  = (const int*)d_in[4];
    const int*   Simp  = (const int*)d_in[5];
    // ws: counts[256] ints @0 | partials[1536] f32 @1024 | Ibf bf16 @8192
    int*   counts   = (int*)d_ws;
    float* partials = (float*)((char*)d_ws + 1024);
    size_t need_bf16 = 8192 + (size_t)B * L * D * sizeof(unsigned short);

    if (ws_size >= need_bf16) {
        unsigned short* Ibf = (unsigned short*)((char*)d_ws + 8192);
        prep_kernel<<<B + 512, 256, 0, stream>>>(tmask, imask, I, counts, Ibf);
        sim_kernel_bf16<<<3 * B * 4, 256, 0, stream>>>(T, Ibf, counts, Iimp, Simp, partials);
    } else {
        count_kernel<<<B, 256, 0, stream>>>(tmask, imask, counts);
        sim_kernel_f32<<<3 * B * 4, 256, 0, stream>>>(T, I, counts, Iimp, Simp, partials);
    }
    loss_kernel<<<1, 384, 0, stream>>>(partials, (float*)d_out);
}

// Round 13
// 140.024 us; speedup vs baseline: 1.6142x; 1.6142x over previous
//
#include <hip/hip_runtime.h>
#include <hip/hip_bf16.h>

#define B 128
#define N 1024
#define L 512
#define D 64

typedef float f32x4 __attribute__((ext_vector_type(4)));
typedef short bf16x8 __attribute__((ext_vector_type(8)));

// 8 fp32 -> 8 bf16 (RNE) via packed HW cvt
__device__ inline bf16x8 cvt8(float4 f0, float4 f1) {
    union { __hip_bfloat162 h2[4]; bf16x8 v; } u;
    u.h2[0] = __float22bfloat162_rn(make_float2(f0.x, f0.y));
    u.h2[1] = __float22bfloat162_rn(make_float2(f0.z, f0.w));
    u.h2[2] = __float22bfloat162_rn(make_float2(f1.x, f1.y));
    u.h2[3] = __float22bfloat162_rn(make_float2(f1.z, f1.w));
    return u.v;
}

// async global->LDS DMA, 16B per lane; LDS dest = wave-uniform base + lane*16
__device__ __forceinline__ void gload16(const void* g, void* l) {
    __builtin_amdgcn_global_load_lds(
        (const __attribute__((address_space(1))) void*)g,
        (__attribute__((address_space(3))) void*)l, 16, 0, 0);
}

// ============================ bf16-workspace path ============================
// Fused pre-pass: blocks [0,B): mask counts; blocks [B,B+512): I fp32->bf16.
__global__ __launch_bounds__(256) void prep_kernel(
        const float* __restrict__ tmask, const float* __restrict__ imask,
        const float* __restrict__ I,
        int* __restrict__ counts, unsigned short* __restrict__ Ibf) {
    int blk = blockIdx.x, tid = threadIdx.x;
    if (blk < B) {
        int b = blk;
        int w = tid >> 6, lane = tid & 63;
        float ts = 0.f, is = 0.f;
        const float* tm = tmask + (size_t)b * N;
#pragma unroll
        for (int i = 0; i < N / 256; ++i) ts += tm[tid + i * 256];
        const float* im = imask + (size_t)b * L;
#pragma unroll
        for (int i = 0; i < L / 256; ++i) is += im[tid + i * 256];
        for (int off = 32; off; off >>= 1) {
            ts += __shfl_down(ts, off);
            is += __shfl_down(is, off);
        }
        __shared__ float red[8];
        if (lane == 0) { red[w] = ts; red[4 + w] = is; }
        __syncthreads();
        if (tid == 0) counts[b]     = (int)(red[0] + red[1] + red[2] + red[3] + 0.5f);
        if (tid == 1) counts[B + b] = (int)(red[4] + red[5] + red[6] + red[7] + 0.5f);
    } else {
        int t = (blk - B) * 256 + tid;                 // 0..131071
#pragma unroll
        for (int j = 0; j < 4; ++j) {
            size_t ci = (size_t)t + (size_t)j * 131072;
            const float4* p = (const float4*)(I + ci * 8);
            *(bf16x8*)(Ibf + ci * 8) = cvt8(p[0], p[1]);
        }
    }
}

// grid = 1536 blocks (s,b,token-chunk) x 256 thr.
// r12 structure with the SPILL FIXED: __launch_bounds__(256,6) not (256,8).
// r12's lb(256,8) capped VGPR at 32 (< the ~56 the kernel needs: afrag=32 +
// mx=16 + addressing) -> full scratch spill (WRITE_SIZE 180MB, 141us). At 6
// waves/EU the cap is ~85 VGPR -> no spill, and LDS 12.4KB still admits 6
// blocks/CU x 256 CU = 1536 = WHOLE GRID co-resident (24 waves/CU, 3x the
// r8/r9 TLP that plateaued at ~40us, without r11's 4x redundant staging).
// Block-cooperative 32-region (4KB) chunks, 3-buffer counted-vmcnt pipeline:
// prologue stage(0,1) [1 gload16/thread each]; iter k: stage(k+2) [3 out];
// end-of-iter wait vmcnt(1) => k+1 landed (k+2 flying) + lgkmcnt(0)+barrier
// protecting the mod-3 rotation (r5/r11-proven hazard ledger).
// Chunk layout (4KB = 32 regions x 64 elems bf16), 16B chunk ci = tid:
//   g=ci>>6 (=rt*2+h, rt in {0,1}), ln=ci&63: region (g>>1)*16+(ln&15),
//   elems (g&1)*32+(ln>>4)*8 .. +8. Conflict-free ds_read_b128 at
//   base+lane*16 + (rt*2+h)*1024.
__global__ __launch_bounds__(256, 6) void sim_kernel_bf16(
        const float* __restrict__ T, const unsigned short* __restrict__ Ibf,
        const int* __restrict__ counts,
        const int* __restrict__ Iimp, const int* __restrict__ Simp,
        float* __restrict__ partials) {
    int blk = blockIdx.x;          // 0..1535
    int chunk = blk & 3;
    int bs = blk >> 2;
    int b = bs & (B - 1);
    int s = bs >> 7;
    int Tb = b, Ib = b;
    if (s == 1) Tb = Simp[b];
    else if (s == 2) Ib = Iimp[b];

    int tid = threadIdx.x;
    int w = tid >> 6;
    int lane = tid & 63;
    int q = lane >> 4;
    int c = lane & 15;

    int ntok = counts[Tb];         // block-uniform
    int nreg = counts[B + Ib];

    int tok0 = chunk << 8;
    if (chunk != 0 && tok0 >= ntok) {      // ntok >= 256: chunk 0 never exits
        if (tid == 0) partials[blk] = 0.f;
        return;
    }

    __shared__ unsigned short ldsI[3][2048];     // 3 x 4KB bf16 chunk buffers
    __shared__ float red[4];

    // ---- A fragments: 4 token tiles x 2 K-halves (rows >= ntok masked at sum)
    int wt0 = tok0 + w * 64;
    bf16x8 afrag[4][2];
#pragma unroll
    for (int tt = 0; tt < 4; ++tt) {
        const float* trow = T + ((size_t)Tb * N + wt0 + tt * 16 + c) * D;
#pragma unroll
        for (int h = 0; h < 2; ++h) {
            const float4* p = (const float4*)(trow + h * 32 + q * 8);
            afrag[tt][h] = cvt8(p[0], p[1]);
        }
    }

    float mx[4][4];
#pragma unroll
    for (int tt = 0; tt < 4; ++tt)
#pragma unroll
        for (int i = 0; i < 4; ++i) mx[tt][i] = -3.0e38f;

    // ---- staging decode: 1 x 16B DMA per thread per 32-region chunk ----
    int g = tid >> 6, ln = tid & 63;
    int rloc = (g >> 1) * 16 + (ln & 15);
    int eoff = (g & 1) * 32 + (ln >> 4) * 8;
    const unsigned short* Ibase = Ibf + (size_t)Ib * L * D;
    int nch = (nreg + 31) >> 5;                  // 4..16 (nreg >= 128)
    int nregm1 = nreg - 1;

    auto stage = [&](int k) {
        int r = (k << 5) + rloc;
        if (r > nregm1) r = nregm1;              // duplicate valid row: max-neutral
        gload16(Ibase + (size_t)r * D + eoff,
                &ldsI[k % 3][0] + (size_t)tid * 8);
    };

    // isolate stage ops in the vmcnt counter (afrag/counts loads all consumed)
    asm volatile("s_waitcnt vmcnt(0)" ::: "memory");
    stage(0);
    stage(1);
    asm volatile("s_waitcnt vmcnt(1)" ::: "memory");   // chunk 0 landed
    __builtin_amdgcn_s_barrier();

    for (int k = 0; k < nch; ++k) {
        if (k + 2 < nch) stage(k + 2);           // depth-2: issue over compute

        // 32-region chunk: 4 ds_read_b128 (conflict-free) + 16 MFMA
        const char* base = (const char*)&ldsI[k % 3][0] + (size_t)lane * 16;
#pragma unroll
        for (int rt = 0; rt < 2; ++rt) {
            bf16x8 b0 = *(const bf16x8*)(base + (rt * 2 + 0) * 1024);
            bf16x8 b1 = *(const bf16x8*)(base + (rt * 2 + 1) * 1024);
#pragma unroll
            for (int tt = 0; tt < 4; ++tt) {
                f32x4 acc = {0.f, 0.f, 0.f, 0.f};
                acc = __builtin_amdgcn_mfma_f32_16x16x32_bf16(afrag[tt][0], b0, acc, 0, 0, 0);
                acc = __builtin_amdgcn_mfma_f32_16x16x32_bf16(afrag[tt][1], b1, acc, 0, 0, 0);
#pragma unroll
                for (int i = 0; i < 4; ++i) mx[tt][i] = fmaxf(mx[tt][i], acc[i]);
            }
        }

        if (k + 1 < nch) {
            // need stage(k+1) landed; stage(k+2) (1 instr/wave) may fly on.
            // lgkmcnt(0): all waves' ds_reads done before barrier -> mod-3 safe
            if (k + 2 < nch)
                asm volatile("s_waitcnt vmcnt(1) lgkmcnt(0)" ::: "memory");
            else
                asm volatile("s_waitcnt vmcnt(0) lgkmcnt(0)" ::: "memory");
            __builtin_amdgcn_s_barrier();
        }
    }

    // ---- cross-lane max over 16 region-cols ----
#pragma unroll
    for (int m = 1; m < 16; m <<= 1) {
#pragma unroll
        for (int tt = 0; tt < 4; ++tt)
#pragma unroll
            for (int i = 0; i < 4; ++i)
                mx[tt][i] = fmaxf(mx[tt][i], __shfl_xor(mx[tt][i], m));
    }

    // ---- masked token sum (C layout: row = q*4 + i) ----
    float bsum = 0.f;
    if (c == 0) {
#pragma unroll
        for (int tt = 0; tt < 4; ++tt)
#pragma unroll
            for (int i = 0; i < 4; ++i) {
                int row = wt0 + tt * 16 + q * 4 + i;
                if (row < ntok) bsum += mx[tt][i];
            }
    }
    for (int off = 32; off; off >>= 1) bsum += __shfl_down(bsum, off);
    if (lane == 0) red[w] = bsum;
    __syncthreads();
    if (tid == 0)
        partials[blk] = (red[0] + red[1] + red[2] + red[3]) / (float)ntok;
}

// ===================== fallback path (tiny workspace, r3) =====================
__global__ __launch_bounds__(256) void count_kernel(
        const float* __restrict__ tmask, const float* __restrict__ imask,
        int* __restrict__ counts) {
    int b = blockIdx.x, tid = threadIdx.x;
    int w = tid >> 6, lane = tid & 63;
    float ts = 0.f, is = 0.f;
    const float* tm = tmask + (size_t)b * N;
#pragma unroll
    for (int i = 0; i < N / 256; ++i) ts += tm[tid + i * 256];
    const float* im = imask + (size_t)b * L;
#pragma unroll
    for (int i = 0; i < L / 256; ++i) is += im[tid + i * 256];
    for (int off = 32; off; off >>= 1) {
        ts += __shfl_down(ts, off);
        is += __shfl_down(is, off);
    }
    __shared__ float red[8];
    if (lane == 0) { red[w] = ts; red[4 + w] = is; }
    __syncthreads();
    if (tid == 0) counts[b]     = (int)(red[0] + red[1] + red[2] + red[3] + 0.5f);
    if (tid == 1) counts[B + b] = (int)(red[4] + red[5] + red[6] + red[7] + 0.5f);
}

// verbatim round-3 sim kernel (passed): fp32 DMA staging, 3x16KB LDS
__global__ __launch_bounds__(256, 3) void sim_kernel_f32(
        const float* __restrict__ T, const float* __restrict__ I,
        const int* __restrict__ counts,
        const int* __restrict__ Iimp, const int* __restrict__ Simp,
        float* __restrict__ partials) {
    int blk = blockIdx.x;
    int chunk = blk & 3;
    int bs = blk >> 2;
    int b = bs & (B - 1);
    int s = bs >> 7;
    int Tb = b, Ib = b;
    if (s == 1) Tb = Simp[b];
    else if (s == 2) Ib = Iimp[b];

    int tid = threadIdx.x;
    int w = tid >> 6;
    int lane = tid & 63;
    int q = lane >> 4;
    int c = lane & 15;

    int ntok = counts[Tb];
    int nreg = counts[B + Ib];

    int tok0 = chunk << 8;
    if (chunk != 0 && tok0 >= ntok) {
        if (tid == 0) partials[blk] = 0.f;
        return;
    }

    __shared__ float ldsI[3][4096];
    __shared__ float red[4];

    int wt0 = tok0 + w * 64;
    bf16x8 afrag[4][2];
#pragma unroll
    for (int tt = 0; tt < 4; ++tt) {
        const float* trow = T + ((size_t)Tb * N + wt0 + tt * 16 + c) * D;
#pragma unroll
        for (int h = 0; h < 2; ++h) {
            const float4* p = (const float4*)(trow + h * 32 + q * 8);
            afrag[tt][h] = cvt8(p[0], p[1]);
        }
    }

    float mx[4][4];
#pragma unroll
    for (int tt = 0; tt < 4; ++tt)
#pragma unroll
        for (int i = 0; i < 4; ++i) mx[tt][i] = -3.0e38f;

    int rloc[4], foff[4];
#pragma unroll
    for (int j = 0; j < 4; ++j) {
        int ci = tid + j * 256;
        int fh = ci >> 7, idx = ci & 127, half = idx >> 6, ln2 = idx & 63;
        rloc[j] = (fh >> 1) * 16 + (ln2 & 15);
        foff[j] = (fh & 1) * 32 + (ln2 >> 4) * 8 + half * 4;
    }
    const float* Ibase = I + (size_t)Ib * L * D;
    int nchunks = (nreg + 63) >> 6;
    int nregm1 = nreg - 1;

    auto stage = [&](int k) {
        float* buf = &ldsI[k % 3][0];
        int rbase = k << 6;
#pragma unroll
        for (int j = 0; j < 4; ++j) {
            int r = rbase + rloc[j];
            if (r > nregm1) r = nregm1;
            gload16(Ibase + (size_t)r * D + foff[j], buf + (tid + j * 256) * 4);
        }
    };

    asm volatile("s_waitcnt vmcnt(0)" ::: "memory");
    stage(0);
    stage(1);
    asm volatile("s_waitcnt vmcnt(4)" ::: "memory");
    __builtin_amdgcn_s_barrier();

    for (int k = 0; k < nchunks; ++k) {
        if (k + 2 < nchunks) stage(k + 2);

        const char* base = (const char*)&ldsI[k % 3][0] + (size_t)lane * 16;
#pragma unroll
        for (int rt = 0; rt < 4; ++rt) {
            float4 e0 = *(const float4*)(base + (rt * 2 + 0) * 2048);
            float4 e1 = *(const float4*)(base + (rt * 2 + 0) * 2048 + 1024);
            float4 e2 = *(const float4*)(base + (rt * 2 + 1) * 2048);
            float4 e3 = *(const float4*)(base + (rt * 2 + 1) * 2048 + 1024);
            bf16x8 b0 = cvt8(e0, e1);
            bf16x8 b1 = cvt8(e2, e3);
#pragma unroll
            for (int tt = 0; tt < 4; ++tt) {
                f32x4 acc = {0.f, 0.f, 0.f, 0.f};
                acc = __builtin_amdgcn_mfma_f32_16x16x32_bf16(afrag[tt][0], b0, acc, 0, 0, 0);
                acc = __builtin_amdgcn_mfma_f32_16x16x32_bf16(afrag[tt][1], b1, acc, 0, 0, 0);
#pragma unroll
                for (int i = 0; i < 4; ++i) mx[tt][i] = fmaxf(mx[tt][i], acc[i]);
            }
        }

        if (k + 1 < nchunks) {
            if (k + 2 < nchunks)
                asm volatile("s_waitcnt vmcnt(4) lgkmcnt(0)" ::: "memory");
            else
                asm volatile("s_waitcnt vmcnt(0) lgkmcnt(0)" ::: "memory");
            __builtin_amdgcn_s_barrier();
        }
    }

#pragma unroll
    for (int m = 1; m < 16; m <<= 1) {
#pragma unroll
        for (int tt = 0; tt < 4; ++tt)
#pragma unroll
            for (int i = 0; i < 4; ++i)
                mx[tt][i] = fmaxf(mx[tt][i], __shfl_xor(mx[tt][i], m));
    }

    float bsum = 0.f;
    if (c == 0) {
#pragma unroll
        for (int tt = 0; tt < 4; ++tt)
#pragma unroll
            for (int i = 0; i < 4; ++i) {
                int row = wt0 + tt * 16 + q * 4 + i;
                if (row < ntok) bsum += mx[tt][i];
            }
    }
    for (int off = 32; off; off >>= 1) bsum += __shfl_down(bsum, off);
    if (lane == 0) red[w] = bsum;
    __syncthreads();
    if (tid == 0)
        partials[blk] = (red[0] + red[1] + red[2] + red[3]) / (float)ntok;
}

// 1 block x 384 threads: fold 1536 partials -> 384 sims -> hinge -> loss
__global__ void loss_kernel(const float* __restrict__ partials,
                            float* __restrict__ out) {
    int tid = threadIdx.x;  // 0..383
    __shared__ float simsL[384];
    __shared__ float w6[6];
    const float4* p4 = (const float4*)partials;
    float4 v = p4[tid];
    simsL[tid] = v.x + v.y + v.z + v.w;
    __syncthreads();
    float per = 0.f;
    if (tid < B) {
        float anc  = simsL[tid];
        float simp = simsL[B + tid];
        float iimp = simsL[2 * B + tid];
        per = fmaxf(1.f + iimp - anc, 0.f) + fmaxf(1.f + simp - anc, 0.f);
    }
    for (int off = 32; off; off >>= 1) per += __shfl_down(per, off);
    if ((tid & 63) == 0) w6[tid >> 6] = per;
    __syncthreads();
    if (tid == 0)
        out[0] = (w6[0] + w6[1] + w6[2] + w6[3] + w6[4] + w6[5]) / (float)B;
}

extern "C" void kernel_launch(void* const* d_in, const int* in_sizes, int n_in,
                              void* d_out, int out_size, void* d_ws, size_t ws_size,
                              hipStream_t stream) {
    const float* T     = (const float*)d_in[0];
    const float* I     = (const float*)d_in[1];
    const float* tmask = (const float*)d_in[2];
    const float* imask = (const float*)d_in[3];
    const int*   Iimp  = (const int*)d_in[4];
    const int*   Simp  = (const int*)d_in[5];
    // ws: counts[256] ints @0 | partials[1536] f32 @1024 | Ibf bf16 @8192
    int*   counts   = (int*)d_ws;
    float* partials = (float*)((char*)d_ws + 1024);
    size_t need_bf16 = 8192 + (size_t)B * L * D * sizeof(unsigned short);

    if (ws_size >= need_bf16) {
        unsigned short* Ibf = (unsigned short*)((char*)d_ws + 8192);
        prep_kernel<<<B + 512, 256, 0, stream>>>(tmask, imask, I, counts, Ibf);
        sim_kernel_bf16<<<3 * B * 4, 256, 0, stream>>>(T, Ibf, counts, Iimp, Simp, partials);
    } else {
        count_kernel<<<B, 256, 0, stream>>>(tmask, imask, counts);
        sim_kernel_f32<<<3 * B * 4, 256, 0, stream>>>(T, I, counts, Iimp, Simp, partials);
    }
    loss_kernel<<<1, 384, 0, stream>>>(partials, (float*)d_out);
}